// Round 3
// baseline (160.149 us; speedup 1.0000x reference)
//
#include <hip/hip_runtime.h>
#include <math.h>

#define B_ 2
#define T_ 16
#define N_ 128
#define CI 64
#define CO 128

// ws layout (floats):
//   A    @ 0        : 524288   [b,t,n,o]  (bias folded)
//   Bp   @ 524288   : 524288   [b,t,n,o]
//   WT   @ 1048576  : 49152    3 x [c][256] effective x-weights (cls 0=t0,1=mid,2=tlast)
//   WcT  @ 1097728  : 16384    2 x [o][c]  transposed cond-weights (p 0=Wc1,1=Wc2)
//   Cp   @ 1114112  : 4194304  [b,i,j,o]
#define A_OFF   0
#define BP_OFF  524288
#define WT_OFF  1048576
#define WCT_OFF 1097728
#define CP_OFF  1114112

__device__ __forceinline__ float4 f4add(float4 a, float4 b) {
  return make_float4(a.x + b.x, a.y + b.y, a.z + b.z, a.w + b.w);
}
__device__ __forceinline__ float4 f4max(float4 a, float4 b) {
  return make_float4(fmaxf(a.x, b.x), fmaxf(a.y, b.y), fmaxf(a.z, b.z), fmaxf(a.w, b.w));
}
__device__ __forceinline__ void f4fma(float4& acc, float s, float4 v) {
  acc.x = fmaf(s, v.x, acc.x);
  acc.y = fmaf(s, v.y, acc.y);
  acc.z = fmaf(s, v.z, acc.z);
  acc.w = fmaf(s, v.w, acc.w);
}

// =====================================================================
// k_prep (64 blocks x 256):
//  blocks 0..47 : WT[cls][c][oo]  (oo<128 -> Weff1 col o, oo>=128 -> Weff2)
//  blocks 48..63: WcT[p][o][c] transpose of W rows 384..512
// =====================================================================
__global__ __launch_bounds__(256) void k_prep(const float* __restrict__ W,
                                              float* __restrict__ WT,
                                              float* __restrict__ WcT) {
  int blk = blockIdx.x;
  int tid = threadIdx.x;
  if (blk < 48) {
    int e4 = blk * 256 + tid;
    int flat = e4 * 4;
    int cls = flat / 16384;
    int rem = flat - cls * 16384;
    int c = rem >> 8;
    int oo = rem & 255;
    float f0 = (cls == 0) ? 0.0f : 1.0f;
    float f2 = (cls == 2) ? 0.0f : 1.0f;
    const float4* W4 = (const float4*)W;
    int o = oo & 127;
    int base = (oo < 128) ? 0 : 24576;
    int wi = (base + c * 128 + o) >> 2;
    float4 wa = W4[wi];
    float4 wb = W4[wi + 2048];
    float4 wc = W4[wi + 4096];
    ((float4*)WT)[e4] = make_float4(f0 * wa.x + wb.x + f2 * wc.x,
                                    f0 * wa.y + wb.y + f2 * wc.y,
                                    f0 * wa.z + wb.z + f2 * wc.z,
                                    f0 * wa.w + wb.w + f2 * wc.w);
  } else {
    int e0 = ((blk - 48) * 256 + tid) * 4;
    #pragma unroll
    for (int k = 0; k < 4; k++) {
      int e = e0 + k;
      int p = e >> 13;
      int rem = e & 8191;
      int o = rem >> 6;
      int c = rem & 63;
      WcT[e] = W[49152 + p * 8192 + c * 128 + o];
    }
  }
}

// =====================================================================
// k_ab: grid 1024 = b(2) x t(16) x nt(16, 8 rows) x oh(2: 0->A, 1->Bp)
// 128 thr; thread = 2 rows x 1 o-quad. LDS 35KB -> 4 blocks/CU, 8 waves/CU.
// WL staging start is skewed per block (hot-line decorrelation).
// =====================================================================
__global__ __launch_bounds__(128) void k_ab(
    const float* __restrict__ x, const float* __restrict__ WT,
    const float* __restrict__ bias, float* __restrict__ A, float* __restrict__ Bp)
{
  __shared__ __align__(16) float WL[64 * 128];   // [c][o]
  __shared__ __align__(16) float xT[64 * 12];    // [c][r], stride 12 (48B)

  int blk = blockIdx.x;
  int oh = blk & 1;
  int nt = (blk >> 1) & 15;
  int t  = (blk >> 5) & 15;
  int b  = blk >> 9;
  int n0 = nt * 8;
  int cls = (t == 0) ? 0 : ((t == T_ - 1) ? 2 : 1);
  int tid = threadIdx.x;

  // stage weights half (2048 float4), skewed start
  {
    const float4* WT4 = (const float4*)WT;
    float4* WL4 = (float4*)WL;
    int sk = (blk * 73) & 2047;
    int wbase = cls * 4096 + oh * 32;
    #pragma unroll
    for (int k = 0; k < 16; k++) {
      int ii = (tid + k * 128 + sk) & 2047;
      int c = ii >> 5, q4 = ii & 31;
      WL4[c * 32 + q4] = WT4[wbase + c * 64 + q4];
    }
  }
  // stage x rows transposed: xT[c][r]
  {
    long xb = ((long)(b * T_ + t) * N_ + n0) * CI;
    #pragma unroll
    for (int k = 0; k < 4; k++) {
      int idx = tid + k * 128;
      int r = idx >> 6, c = idx & 63;
      xT[c * 12 + r] = x[xb + r * CI + c];
    }
  }
  __syncthreads();

  int rg = tid >> 5;          // 0..3 -> rows 2rg, 2rg+1
  int q  = tid & 31;          // o-quad
  int r0 = rg * 2;

  float4 acc0, acc1;
  if (oh == 0) {
    float4 bq = *(const float4*)&bias[q * 4];
    acc0 = bq; acc1 = bq;
  } else {
    acc0 = make_float4(0, 0, 0, 0); acc1 = acc0;
  }

  const float4* WL4 = (const float4*)WL;
  #pragma unroll 8
  for (int c = 0; c < CI; c++) {
    float x0 = xT[c * 12 + r0];
    float x1 = xT[c * 12 + r0 + 1];
    float4 wv = WL4[c * 32 + q];
    f4fma(acc0, x0, wv);
    f4fma(acc1, x1, wv);
  }

  float* dst = (oh == 0) ? A : Bp;
  long rb = ((long)(b * T_ + t) * N_ + n0 + r0) * CO + q * 4;
  *(float4*)&dst[rb]      = acc0;
  *(float4*)&dst[rb + CO] = acc1;
}

// =====================================================================
// k_cp: Cp[b,i,j,o] = cond[b,i,j,:]@Wc1 + cond[b,j,i,:]@Wc2
// grid 1024 = b(2) x i(128) x jh(2) x ohf(2); 256 thr; tile 4j x 4o.
// LDS 35KB -> 4 blocks/CU, 16 waves/CU. Staging skewed.
// =====================================================================
__device__ __forceinline__ void gemm4x4(float acc[4][4], const float* Wt,
                                        const float* Cd, int jg, int og) {
  for (int c = 0; c < 64; c += 4) {
    float4 wv[4], cv[4];
    #pragma unroll
    for (int m = 0; m < 4; m++) wv[m] = *(const float4*)&Wt[(og * 4 + m) * 68 + c];
    #pragma unroll
    for (int k = 0; k < 4; k++) cv[k] = *(const float4*)&Cd[(jg * 4 + k) * 68 + c];
    #pragma unroll
    for (int k = 0; k < 4; k++) {
      #pragma unroll
      for (int m = 0; m < 4; m++) {
        acc[k][m] = fmaf(cv[k].x, wv[m].x, acc[k][m]);
        acc[k][m] = fmaf(cv[k].y, wv[m].y, acc[k][m]);
        acc[k][m] = fmaf(cv[k].z, wv[m].z, acc[k][m]);
        acc[k][m] = fmaf(cv[k].w, wv[m].w, acc[k][m]);
      }
    }
  }
}

__global__ __launch_bounds__(256) void k_cp(
    const float* __restrict__ cond, const float* __restrict__ WcT,
    float* __restrict__ Cp)
{
  __shared__ __align__(16) float Wt[64 * 68];    // [o_local][c]
  __shared__ __align__(16) float Cd[64 * 68];    // [j_local][c]

  int blk = blockIdx.x;
  int ohf = blk & 1;
  int jh  = (blk >> 1) & 1;
  int i   = (blk >> 2) & 127;
  int b   = blk >> 9;
  int tid = threadIdx.x;
  int jg = tid >> 4;   // 0..15
  int og = tid & 15;   // 0..15

  float acc[4][4];
  #pragma unroll
  for (int k = 0; k < 4; k++)
    #pragma unroll
    for (int m = 0; m < 4; m++) acc[k][m] = 0.0f;

  const float4* WcT4 = (const float4*)WcT;
  const float4* cond4 = (const float4*)cond;
  float4* Wt4 = (float4*)Wt;
  float4* Cd4 = (float4*)Cd;
  int sk = (blk * 193) & 1023;

  // ---- pass 1: cond[b,i,jh*64+jl,:] @ Wc1 ----
  #pragma unroll
  for (int k = 0; k < 4; k++) {
    int ii = (tid + k * 256 + sk) & 1023;
    int ol = ii >> 4, c4 = ii & 15;
    Wt4[ol * 17 + c4] = WcT4[(0 * 128 + ohf * 64 + ol) * 16 + c4];
  }
  {
    long cb = ((long)(b * N_ + i) * N_ + jh * 64) * CI / 4;
    #pragma unroll
    for (int k = 0; k < 4; k++) {
      int ii = tid + k * 256;
      int jl = ii >> 4, c4 = ii & 15;
      Cd4[jl * 17 + c4] = cond4[cb + jl * 16 + c4];
    }
  }
  __syncthreads();
  gemm4x4(acc, Wt, Cd, jg, og);
  __syncthreads();

  // ---- pass 2: cond[b,jh*64+jl,i,:] @ Wc2 ----
  #pragma unroll
  for (int k = 0; k < 4; k++) {
    int ii = (tid + k * 256 + sk) & 1023;
    int ol = ii >> 4, c4 = ii & 15;
    Wt4[ol * 17 + c4] = WcT4[(1 * 128 + ohf * 64 + ol) * 16 + c4];
  }
  {
    long cb0 = ((long)b * N_ + jh * 64) * N_ * (CI / 4);
    #pragma unroll
    for (int k = 0; k < 4; k++) {
      int ii = tid + k * 256;
      int jl = ii >> 4, c4 = ii & 15;
      Cd4[jl * 17 + c4] = cond4[cb0 + ((long)jl * N_ + i) * 16 + c4];
    }
  }
  __syncthreads();
  gemm4x4(acc, Wt, Cd, jg, og);

  // ---- store ----
  long base = ((long)(b * N_ + i) * N_ + jh * 64) * CO + ohf * 64 + og * 4;
  #pragma unroll
  for (int k = 0; k < 4; k++) {
    float4 r = make_float4(acc[k][0], acc[k][1], acc[k][2], acc[k][3]);
    *(float4*)&Cp[base + (long)(jg * 4 + k) * CO] = r;
  }
}

// =====================================================================
// k_red: out[b,t,i,o] = silu( A[t,i,o] + max_j(Bp[t,j,o] + Cp[i,j,o]) )
// grid 512 = b(2) x i(128) x th(2); 512 thr (8 waves; t = th*8 + wave).
// LDS 64KB -> 2 blocks/CU, 16 waves/CU.
// j-scan start skewed per (i,t) to decorrelate L2 slice traffic.
// =====================================================================
__device__ float slow_silu_max(const float* __restrict__ BpT,
                               const float* __restrict__ CpS, float a, int o) {
  float m = -3.4e38f;
  for (int j = 0; j < 128; j++) {
    float v = a + BpT[j * CO + o] + CpS[j * CO + o];
    float sil = v / (1.0f + __expf(-v));
    m = fmaxf(m, sil);
  }
  return m;
}
__device__ __forceinline__ float fast_silu(float s) {
  return s / (1.0f + __expf(-s));
}

__global__ __launch_bounds__(512) void k_red(
    const float* __restrict__ A, const float* __restrict__ Bp,
    const float* __restrict__ Cp, float* __restrict__ out)
{
  __shared__ __align__(16) float CpL[128 * 128];  // 64 KB

  int blk = blockIdx.x;
  int th = blk & 1;
  int i  = (blk >> 1) & 127;
  int b  = blk >> 8;
  int tid = threadIdx.x;

  // stage Cp[b,i,:,:] (4096 float4), skewed start
  {
    const float4* src = (const float4*)(Cp + ((long)(b * N_ + i)) * N_ * CO);
    float4* CpL4 = (float4*)CpL;
    int sk = (blk * 97) & 4095;
    #pragma unroll
    for (int k = 0; k < 8; k++) {
      int ii = (tid + k * 512 + sk) & 4095;
      CpL4[ii] = src[ii];
    }
  }
  __syncthreads();

  int t    = th * 8 + (tid >> 6);
  int lane = tid & 63;
  int jh   = lane >> 5;
  int o4   = lane & 31;
  int laneoff = jh * 2048 + o4;

  const float* BpT = Bp + (long)(b * T_ + t) * N_ * CO;
  const float4* Bp4 = (const float4*)BpT;
  const float4* CpL4 = (const float4*)CpL;

  int skewj = (i * 37 + t * 11) & 63;

  float4 m0 = make_float4(-3.4e38f, -3.4e38f, -3.4e38f, -3.4e38f);
  float4 m1 = m0, m2 = m0, m3 = m0;
  #pragma unroll 2
  for (int jj = 0; jj < 64; jj += 4) {
    int i0 = laneoff + (((jj + 0 + skewj) & 63) << 5);
    int i1 = laneoff + (((jj + 1 + skewj) & 63) << 5);
    int i2 = laneoff + (((jj + 2 + skewj) & 63) << 5);
    int i3 = laneoff + (((jj + 3 + skewj) & 63) << 5);
    m0 = f4max(m0, f4add(Bp4[i0], CpL4[i0]));
    m1 = f4max(m1, f4add(Bp4[i1], CpL4[i1]));
    m2 = f4max(m2, f4add(Bp4[i2], CpL4[i2]));
    m3 = f4max(m3, f4add(Bp4[i3], CpL4[i3]));
  }
  float4 m = f4max(f4max(m0, m1), f4max(m2, m3));
  float4 mo;
  mo.x = __shfl_xor(m.x, 32, 64);
  mo.y = __shfl_xor(m.y, 32, 64);
  mo.z = __shfl_xor(m.z, 32, 64);
  mo.w = __shfl_xor(m.w, 32, 64);
  m = f4max(m, mo);

  long abase = ((long)(b * T_ + t) * N_ + i) * CO + o4 * 4;
  float4 av = *(const float4*)&A[abase];
  float4 s = f4add(m, av);
  if (jh == 0) {
    float4 r;
    r.x = (s.x >= 0.0f) ? fast_silu(s.x) : slow_silu_max(BpT, CpL, av.x, o4 * 4 + 0);
    r.y = (s.y >= 0.0f) ? fast_silu(s.y) : slow_silu_max(BpT, CpL, av.y, o4 * 4 + 1);
    r.z = (s.z >= 0.0f) ? fast_silu(s.z) : slow_silu_max(BpT, CpL, av.z, o4 * 4 + 2);
    r.w = (s.w >= 0.0f) ? fast_silu(s.w) : slow_silu_max(BpT, CpL, av.w, o4 * 4 + 3);
    *(float4*)&out[abase] = r;
  }
}

extern "C" void kernel_launch(void* const* d_in, const int* in_sizes, int n_in,
                              void* d_out, int out_size, void* d_ws, size_t ws_size,
                              hipStream_t stream) {
  const float* x    = (const float*)d_in[0];   // (2,16,128,64)
  const float* cond = (const float*)d_in[1];   // (2,128,128,64)
  const float* W    = (const float*)d_in[2];   // (512,128)
  const float* bias = (const float*)d_in[3];   // (128,)
  float* out = (float*)d_out;                  // (2,16,128,128)

  float* ws  = (float*)d_ws;
  float* A   = ws + A_OFF;
  float* Bp  = ws + BP_OFF;
  float* WT  = ws + WT_OFF;
  float* WcT = ws + WCT_OFF;
  float* Cp  = ws + CP_OFF;

  k_prep<<<64, 256, 0, stream>>>(W, WT, WcT);
  k_ab<<<1024, 128, 0, stream>>>(x, WT, bias, A, Bp);
  k_cp<<<1024, 256, 0, stream>>>(cond, WcT, Cp);
  k_red<<<512, 512, 0, stream>>>(A, Bp, Cp, out);
}

// Round 4
// 110.246 us; speedup vs baseline: 1.4526x; 1.4526x over previous
//
#include <hip/hip_runtime.h>
#include <math.h>

#define B_ 2
#define T_ 16
#define N_ 128
#define CI 64
#define CO 128

// ws layout (floats), all o-quad-major for coalesced consumption:
//   AQ @ 0       : 524288   AQ[b][oq32][t16][n128][4]  (a + bias)
//   BQ @ 524288  : 524288   BQ[b][oq32][t16][j128][4]  (bpart)
//   CQ @ 1048576 : 4194304  CQ[b][oq32][i128][j128][4] (cpart)
#define AQ_OFF 0
#define BQ_OFF 524288
#define CQ_OFF 1048576

__device__ __forceinline__ float4 f4add(float4 a, float4 b) {
  return make_float4(a.x + b.x, a.y + b.y, a.z + b.z, a.w + b.w);
}
__device__ __forceinline__ float4 f4max(float4 a, float4 b) {
  return make_float4(fmaxf(a.x, b.x), fmaxf(a.y, b.y), fmaxf(a.z, b.z), fmaxf(a.w, b.w));
}
__device__ __forceinline__ float4 f4min(float4 a, float4 b) {
  return make_float4(fminf(a.x, b.x), fminf(a.y, b.y), fminf(a.z, b.z), fminf(a.w, b.w));
}
__device__ __forceinline__ void f4fma(float4& acc, float s, float4 v) {
  acc.x = fmaf(s, v.x, acc.x);
  acc.y = fmaf(s, v.y, acc.y);
  acc.z = fmaf(s, v.z, acc.z);
  acc.w = fmaf(s, v.w, acc.w);
}
__device__ __forceinline__ float silu1(float v) { return v / (1.0f + __expf(-v)); }
__device__ __forceinline__ float4 silu4(float4 v) {
  return make_float4(silu1(v.x), silu1(v.y), silu1(v.z), silu1(v.w));
}
__device__ __forceinline__ float4 shfl4x(float4 v, int m) {
  return make_float4(__shfl_xor(v.x, m, 64), __shfl_xor(v.y, m, 64),
                     __shfl_xor(v.z, m, 64), __shfl_xor(v.w, m, 64));
}

// =====================================================================
// k_ab2 (prep fused): A/Bp from x and W directly (W is a pristine input).
// grid 512 = b(2) x t(16) x dst(2: 0->AQ,1->BQ) x nq(8, 16 rows); 256 thr.
// Weff = f0*W[blk0] + W[blk1] + f2*W[blk2] built into LDS per block.
// thread = 1 row x 2 consecutive o-quads. All LDS reads conflict-free:
//   WL4[c*32 + 2qg+k]: 4 distinct units/instr (qg 0..3 in wave), %8 spread.
//   xT stride 17: banks (17c+nl)%32, 16 distinct.
// =====================================================================
__global__ __launch_bounds__(256) void k_ab2(
    const float* __restrict__ x, const float* __restrict__ W,
    const float* __restrict__ bias, float* __restrict__ AQ, float* __restrict__ BQ)
{
  __shared__ __align__(16) float WL[64 * 128];  // [c][o], unit = c*32+u
  __shared__ float xT[64 * 17];                 // [c][n], stride 17

  int blk = blockIdx.x;
  int nq  = blk & 7;
  int dst = (blk >> 3) & 1;
  int t   = (blk >> 4) & 15;
  int b   = blk >> 8;
  float f0 = (t != 0)      ? 1.0f : 0.0f;
  float f2 = (t != T_ - 1) ? 1.0f : 0.0f;
  int tid = threadIdx.x;

  const float4* W4 = (const float4*)W;
  float4* WL4 = (float4*)WL;
  int wb = dst * 6144;                          // dst 0: W rows 0..192; dst 1: 192..384
  #pragma unroll
  for (int k = 0; k < 8; k++) {
    int idx4 = tid + k * 256;                   // 2048 units = [c 64][u 32]
    float4 wa = W4[wb + idx4];
    float4 wm = W4[wb + 2048 + idx4];
    float4 wc = W4[wb + 4096 + idx4];
    WL4[idx4] = make_float4(f0 * wa.x + wm.x + f2 * wc.x,
                            f0 * wa.y + wm.y + f2 * wc.y,
                            f0 * wa.z + wm.z + f2 * wc.z,
                            f0 * wa.w + wm.w + f2 * wc.w);
  }
  {
    long xb = ((long)(b * T_ + t) * N_ + nq * 16) * CI;
    #pragma unroll
    for (int k = 0; k < 4; k++) {
      int idx = tid + k * 256;
      int c = idx & 63, n = idx >> 6;
      xT[c * 17 + n] = x[xb + n * CI + c];
    }
  }
  __syncthreads();

  int nl = tid & 15;
  int qg = tid >> 4;                            // 0..15 -> quads 2qg, 2qg+1
  float4 acc0, acc1;
  if (dst == 0) {
    acc0 = ((const float4*)bias)[qg * 2];
    acc1 = ((const float4*)bias)[qg * 2 + 1];
  } else {
    acc0 = make_float4(0, 0, 0, 0); acc1 = acc0;
  }
  #pragma unroll 8
  for (int c = 0; c < 64; c++) {
    float xv = xT[c * 17 + nl];
    float4 w0 = WL4[c * 32 + qg * 2];
    float4 w1 = WL4[c * 32 + qg * 2 + 1];
    f4fma(acc0, xv, w0);
    f4fma(acc1, xv, w1);
  }
  float* dp = dst ? BQ : AQ;
  int n = nq * 16 + nl;
  long u0 = ((long)(b * 32 + qg * 2) * 16 + t) * 128 + n;
  long u1 = u0 + 16 * 128;
  ((float4*)dp)[u0] = acc0;
  ((float4*)dp)[u1] = acc1;
}

// =====================================================================
// k_cp2: CQ[b][oq][i][j] = cond[b,i,j,:]@Wc1[:,oq] + cond[b,j,i,:]@Wc2[:,oq]
// grid 1024 = b(2) x i(128) x jh(2) x of(2); 128 thr; tile 8j x 1 o-quad.
// W kept natural [c][o] in LDS (no transpose): per c, Cd scalar broadcast x
// W-quad b128. Conflict-free: WL4[c*16+og] (og distinct units, %8 spread);
// Cd stride 65 floats (odd): banks (8jg+k+c)%32 -> 4 distinct per instr.
// =====================================================================
__global__ __launch_bounds__(128) void k_cp2(
    const float* __restrict__ cond, const float* __restrict__ W,
    float* __restrict__ CQ)
{
  __shared__ __align__(16) float WL[64 * 64];   // [c][o_local], unit = c*16+u
  __shared__ float Cd[64 * 65];                 // [j_local][c], stride 65

  int blk = blockIdx.x;
  int of = blk & 1;
  int jh = (blk >> 1) & 1;
  int i  = (blk >> 2) & 127;
  int b  = blk >> 9;
  int tid = threadIdx.x;
  int og = tid & 15;
  int jg = tid >> 4;                            // 0..7

  float4 acc[8];
  #pragma unroll
  for (int k = 0; k < 8; k++) acc[k] = make_float4(0, 0, 0, 0);

  const float4* W4 = (const float4*)W;
  const float4* c4p = (const float4*)cond;
  float4* WL4 = (float4*)WL;

  for (int p = 0; p < 2; p++) {
    #pragma unroll
    for (int k = 0; k < 8; k++) {
      int idx4 = tid + k * 128;                 // 1024 units = [c 64][u 16]
      int c = idx4 >> 4, u = idx4 & 15;
      WL4[idx4] = W4[(384 + p * 64 + c) * 32 + of * 16 + u];
    }
    #pragma unroll
    for (int k = 0; k < 8; k++) {
      int idx4 = tid + k * 128;                 // 1024 units = [jl 64][c4 16]
      int jl = idx4 >> 4, c4 = idx4 & 15;
      long src = (p == 0)
        ? ((long)(b * N_ + i) * N_ + jh * 64 + jl) * 16 + c4
        : ((long)(b * N_ + jh * 64 + jl) * N_ + i) * 16 + c4;
      float4 v = c4p[src];
      float* row = &Cd[jl * 65 + c4 * 4];
      row[0] = v.x; row[1] = v.y; row[2] = v.z; row[3] = v.w;
    }
    __syncthreads();
    for (int c = 0; c < 64; c++) {
      float4 w = WL4[c * 16 + og];
      #pragma unroll
      for (int k = 0; k < 8; k++) {
        float cd = Cd[(jg * 8 + k) * 65 + c];
        f4fma(acc[k], cd, w);
      }
    }
    __syncthreads();
  }
  // store: per-thread 8 consecutive j float4 = 128B contiguous
  int oq = of * 16 + og;
  long base = ((long)(b * 32 + oq) * 128 + i) * 128 + jh * 64 + jg * 8;
  float4* CQ4 = (float4*)CQ;
  #pragma unroll
  for (int k = 0; k < 8; k++) CQ4[base + k] = acc[k];
}

// =====================================================================
// k_red2: out[b,t,i,o] = max_j silu(A + Bp_j + Cp_j)
//       = max( silu(M), silu(Mn) ),  M/Mn = A + max/min_j (Bp_j + Cp_j)
// (silu is V-shaped then increasing -> set-max at interval endpoints; EXACT,
//  branchless -- kills the old divergent 128-iter slow path entirely.)
// grid 512 = b(2) x oq(32) x ic(8 chunks of 16 i); 512 thr = 8 waves.
// BQ slab [16t][128j][quad] = 32KB in LDS (stride 129: full-rate b128);
// CQ rows streamed once, disjoint per block (no inter-block sharing).
// lane = (t = lane>>2, js = lane&3); shfl_xor(1,2) combines j-quarters.
// =====================================================================
__global__ __launch_bounds__(512) void k_red2(
    const float* __restrict__ AQ, const float* __restrict__ BQ,
    const float* __restrict__ CQ, float* __restrict__ out)
{
  __shared__ __align__(16) float BpL[2064 * 4];     // [t][j] units, t-stride 129
  __shared__ __align__(16) float CpL[8 * 132 * 4];  // per-wave row, js-stride 33

  int blk = blockIdx.x;
  int ic = blk & 7;
  int oq = (blk >> 3) & 31;
  int b  = blk >> 8;
  int tid = threadIdx.x;

  const float4* BQ4 = (const float4*)BQ;
  const float4* CQ4 = (const float4*)CQ;
  const float4* AQ4 = (const float4*)AQ;
  float4* BpL4 = (float4*)BpL;
  float4* CpL4 = (float4*)CpL;

  long slab = (long)(b * 32 + oq) * 2048;
  #pragma unroll
  for (int k = 0; k < 4; k++) {
    int idx = tid + k * 512;
    int t = idx >> 7, j = idx & 127;
    BpL4[t * 129 + j] = BQ4[slab + idx];
  }
  __syncthreads();

  int w    = tid >> 6;
  int lane = tid & 63;
  int t    = lane >> 2;
  int js   = lane & 3;
  int cbase = w * 132;

  for (int r = 0; r < 2; r++) {
    int i = ic * 16 + w * 2 + r;
    long crow = ((long)(b * 32 + oq) * 128 + i) * 128;
    {
      int u0 = lane, u1 = lane + 64;
      CpL4[cbase + (u0 >> 5) * 33 + (u0 & 31)] = CQ4[crow + u0];
      CpL4[cbase + (u1 >> 5) * 33 + (u1 & 31)] = CQ4[crow + u1];
    }
    __syncthreads();

    float4 mxa = make_float4(-3.4e38f, -3.4e38f, -3.4e38f, -3.4e38f);
    float4 mxb = mxa;
    float4 mna = make_float4(3.4e38f, 3.4e38f, 3.4e38f, 3.4e38f);
    float4 mnb = mna;
    int bb = t * 129 + js * 32;
    int cb = cbase + js * 33;
    #pragma unroll 4
    for (int jj = 0; jj < 32; jj += 2) {
      float4 s0 = f4add(BpL4[bb + jj],     CpL4[cb + jj]);
      float4 s1 = f4add(BpL4[bb + jj + 1], CpL4[cb + jj + 1]);
      mxa = f4max(mxa, s0); mna = f4min(mna, s0);
      mxb = f4max(mxb, s1); mnb = f4min(mnb, s1);
    }
    float4 mx = f4max(mxa, mxb);
    float4 mn = f4min(mna, mnb);
    mx = f4max(mx, shfl4x(mx, 1)); mn = f4min(mn, shfl4x(mn, 1));
    mx = f4max(mx, shfl4x(mx, 2)); mn = f4min(mn, shfl4x(mn, 2));

    if (js == 0) {
      float4 av = AQ4[slab + t * 128 + i];
      float4 M  = f4add(mx, av);
      float4 Mn = f4add(mn, av);
      float4 res = f4max(silu4(M), silu4(Mn));
      ((float4*)out)[(long)((b * 16 + t) * 128 + i) * 32 + oq] = res;
    }
    __syncthreads();
  }
}

extern "C" void kernel_launch(void* const* d_in, const int* in_sizes, int n_in,
                              void* d_out, int out_size, void* d_ws, size_t ws_size,
                              hipStream_t stream) {
  const float* x    = (const float*)d_in[0];   // (2,16,128,64)
  const float* cond = (const float*)d_in[1];   // (2,128,128,64)
  const float* W    = (const float*)d_in[2];   // (512,128)
  const float* bias = (const float*)d_in[3];   // (128,)
  float* out = (float*)d_out;                  // (2,16,128,128)

  float* ws = (float*)d_ws;
  float* AQ = ws + AQ_OFF;
  float* BQ = ws + BQ_OFF;
  float* CQ = ws + CQ_OFF;

  k_ab2<<<512, 256, 0, stream>>>(x, W, bias, AQ, BQ);
  k_cp2<<<1024, 128, 0, stream>>>(cond, W, CQ);
  k_red2<<<512, 512, 0, stream>>>(AQ, BQ, CQ, out);
}